// Round 5
// baseline (177.422 us; speedup 1.0000x reference)
//
#include <hip/hip_runtime.h>
#include <math.h>

#define T_LEN 256
#define HID 10

typedef float v2f __attribute__((ext_vector_type(2)));

// ds_swizzle compile-time pattern (BitMode): src = ((lane & and) | or) ^ xor
template <int PAT>
__device__ __forceinline__ float swz(float v) {
    return __int_as_float(__builtin_amdgcn_ds_swizzle(__float_as_int(v), PAT));
}

// setup-only accurate softplus
__device__ __forceinline__ float softplus_f(float x) {
    return fmaxf(x, 0.0f) + log1pf(expf(-fabsf(x)));
}
__device__ __forceinline__ float samp(const float* mu, const float* rho,
                                      const float* eps, int i) {
    return mu[i] + softplus_f(rho[i]) * eps[i];
}

// sigmoid = rcp(1 + 2^(-log2e*x)) : mul, exp, add, rcp
__device__ __forceinline__ float fast_sigmoid(float x) {
    float e = __builtin_amdgcn_exp2f(-1.442695040888963f * x);
    return __builtin_amdgcn_rcpf(1.0f + e);
}
// tanh = 1 - 2*rcp(2^(2*log2e*x) + 1)
__device__ __forceinline__ float fast_tanh(float x) {
    float e = __builtin_amdgcn_exp2f(2.885390081777927f * x);
    return fmaf(-2.0f, __builtin_amdgcn_rcpf(e + 1.0f), 1.0f);
}

#define DOTJ(J, HV)                                                    \
    hh.x = hh.y = (HV);                                                \
    a01 = __builtin_elementwise_fma(hh, whh01[J], a01);                \
    a23 = __builtin_elementwise_fma(hh, whh23[J], a23);

// one element's step: compute gates from current h regs, update c/h,
// write h to LDS, then IMMEDIATELY issue next-step h reads (latency is
// covered by the other element's compute — skewed pipeline).
#define ELEM_STEP(H0, H1, H2, XV, CC, HK, HB, WR)                      \
    {                                                                  \
        v2f hh;                                                        \
        hh.x = hh.y = (XV);                                            \
        v2f a01 = __builtin_elementwise_fma(hh, wih01, bb01);          \
        v2f a23 = __builtin_elementwise_fma(hh, wih23, bb23);          \
        DOTJ(0, (H0).x) DOTJ(1, (H0).y) DOTJ(2, (H0).z) DOTJ(3, (H0).w)\
        DOTJ(4, (H1).x) DOTJ(5, (H1).y) DOTJ(6, (H1).z) DOTJ(7, (H1).w)\
        DOTJ(8, (H2).x) DOTJ(9, (H2).y)                                \
        float si = fast_sigmoid(a01.x);                                \
        float sf = fast_sigmoid(a01.y);                                \
        float tg = fast_tanh(a23.x);                                   \
        float so = fast_sigmoid(a23.y);                                \
        (CC) = fmaf(sf, (CC), si * tg);                                \
        (HK) = so * fast_tanh(CC);                                     \
        (WR)[0] = (HK);                                                \
        (H0) = *(const float4*)(HB);                                   \
        (H1) = *(const float4*)((HB) + 4);                             \
        (H2) = *(const float2*)((HB) + 8);                             \
    }

__global__ __launch_bounds__(256) void bayes_lstm_kernel(
    const float* __restrict__ x,
    const float* __restrict__ w_ih_mu, const float* __restrict__ w_ih_rho,
    const float* __restrict__ w_hh_mu, const float* __restrict__ w_hh_rho,
    const float* __restrict__ b_mu,    const float* __restrict__ b_rho,
    const float* __restrict__ eps_ih,  const float* __restrict__ eps_hh,
    const float* __restrict__ eps_b,
    const float* __restrict__ lin_w,   const float* __restrict__ lin_b,
    float* __restrict__ out)
{
    // 16 slots x 2 elems x 20 floats (80B, 16B-aligned bases; writes <=2-way
    // conflicted (free per m136), group-broadcast b128 reads bank-disjoint).
    __shared__ __align__(16) float hbuf[16 * 2 * 20];

    const int tid  = threadIdx.x;
    const int k    = tid & 15;           // hidden unit (active: k < 10)
    const int slot = tid >> 4;           // 0..15
    const int bA   = (blockIdx.x * 16 + slot) * 2;
    const int bB   = bA + 1;

    float* hbA = hbuf + (slot * 2 + 0) * 20;
    float* hbB = hbuf + (slot * 2 + 1) * 20;
    float* wrA = hbA + k;
    float* wrB = hbB + k;

    // ---- sample weights as {i,f} / {g,o} column pairs (zero for k>=10) ----
    v2f whh01[HID], whh23[HID];
    v2f wih01, wih23, bb01, bb23;
    wih01.x = wih01.y = 0.f; wih23.x = wih23.y = 0.f;
    bb01.x = bb01.y = 0.f;   bb23.x = bb23.y = 0.f;
    float lw = 0.f;
#pragma unroll
    for (int j = 0; j < HID; ++j) {
        whh01[j].x = whh01[j].y = 0.f;
        whh23[j].x = whh23[j].y = 0.f;
    }
    if (k < HID) {
        const int c0 = k, c1 = HID + k, c2 = 2 * HID + k, c3 = 3 * HID + k;
        wih01.x = samp(w_ih_mu, w_ih_rho, eps_ih, c0);
        wih01.y = samp(w_ih_mu, w_ih_rho, eps_ih, c1);
        wih23.x = samp(w_ih_mu, w_ih_rho, eps_ih, c2);
        wih23.y = samp(w_ih_mu, w_ih_rho, eps_ih, c3);
        bb01.x  = samp(b_mu, b_rho, eps_b, c0);
        bb01.y  = samp(b_mu, b_rho, eps_b, c1);
        bb23.x  = samp(b_mu, b_rho, eps_b, c2);
        bb23.y  = samp(b_mu, b_rho, eps_b, c3);
#pragma unroll
        for (int j = 0; j < HID; ++j) {
            whh01[j].x = samp(w_hh_mu, w_hh_rho, eps_hh, j * 4 * HID + c0);
            whh01[j].y = samp(w_hh_mu, w_hh_rho, eps_hh, j * 4 * HID + c1);
            whh23[j].x = samp(w_hh_mu, w_hh_rho, eps_hh, j * 4 * HID + c2);
            whh23[j].y = samp(w_hh_mu, w_hh_rho, eps_hh, j * 4 * HID + c3);
        }
        lw = lin_w[k];
    }

    // ---- recurrence state: h in regs (start 0; LDS written before any read) ----
    float4 hA0 = {0,0,0,0}, hA1 = {0,0,0,0};
    float4 hB0 = {0,0,0,0}, hB1 = {0,0,0,0};
    float2 hA2v = {0,0}, hB2v = {0,0};
    float cA = 0.f, cB = 0.f, hkA = 0.f, hkB = 0.f;

    const float* xrA = x + (size_t)bA * T_LEN;
    const float* xrB = x + (size_t)bB * T_LEN;
    // x prefetch, distance 2 (group-uniform addr -> 1 line broadcast, L1-hot)
    float xA0 = xrA[0], xA1 = xrA[1];
    float xB0 = xrB[0], xB1 = xrB[1];

#pragma unroll 16
    for (int t = 0; t < T_LEN; ++t) {
        float xA2 = xrA[(t + 2) & (T_LEN - 1)];
        float xB2 = xrB[(t + 2) & (T_LEN - 1)];
        ELEM_STEP(hA0, hA1, hA2v, xA0, cA, hkA, hbA, wrA)
        ELEM_STEP(hB0, hB1, hB2v, xB0, cB, hkB, hbB, wrB)
        xA0 = xA1; xA1 = xA2;
        xB0 = xB1; xB1 = xB2;
    }

    // ---- linear head: lane k holds final h[k]; xor-swizzle reduce in group ----
    float pa = hkA * lw;                 // lanes >= 10 contribute 0
    float pb = hkB * lw;
    pa += swz<(1 << 10) | 0x1f>(pa);  pb += swz<(1 << 10) | 0x1f>(pb);
    pa += swz<(2 << 10) | 0x1f>(pa);  pb += swz<(2 << 10) | 0x1f>(pb);
    pa += swz<(4 << 10) | 0x1f>(pa);  pb += swz<(4 << 10) | 0x1f>(pb);
    pa += swz<(8 << 10) | 0x1f>(pa);  pb += swz<(8 << 10) | 0x1f>(pb);
    if (k == 0) {
        float b0 = lin_b[0];
        out[bA] = pa + b0;
        out[bB] = pb + b0;
    }
}

extern "C" void kernel_launch(void* const* d_in, const int* in_sizes, int n_in,
                              void* d_out, int out_size, void* d_ws, size_t ws_size,
                              hipStream_t stream) {
    const float* x        = (const float*)d_in[0];
    const float* w_ih_mu  = (const float*)d_in[1];
    const float* w_ih_rho = (const float*)d_in[2];
    const float* w_hh_mu  = (const float*)d_in[3];
    const float* w_hh_rho = (const float*)d_in[4];
    const float* b_mu     = (const float*)d_in[5];
    const float* b_rho    = (const float*)d_in[6];
    const float* eps_ih   = (const float*)d_in[7];
    const float* eps_hh   = (const float*)d_in[8];
    const float* eps_b    = (const float*)d_in[9];
    const float* lin_w    = (const float*)d_in[10];
    const float* lin_b    = (const float*)d_in[11];
    float* out = (float*)d_out;

    const int n_b = in_sizes[0] / T_LEN;     // 8192
    dim3 grid(n_b / 32), block(256);         // 16 slots x 2 elements per block
    hipLaunchKernelGGL(bayes_lstm_kernel, grid, block, 0, stream,
                       x, w_ih_mu, w_ih_rho, w_hh_mu, w_hh_rho, b_mu, b_rho,
                       eps_ih, eps_hh, eps_b, lin_w, lin_b, out);
}